// Round 7
// baseline (130.800 us; speedup 1.0000x reference)
//
#include <hip/hip_runtime.h>

#define DIM    512
#define RANK   64
#define TDIM   1024
#define BB     2
#define NROWS  (BB * TDIM)     // 2048 flattened rows per tensor
#define KSPLIT 4
#define KCH    (DIM / KSPLIT)  // 128 K-columns per proj block

typedef float v4f __attribute__((ext_vector_type(4)));
typedef float v2f __attribute__((ext_vector_type(2)));

__device__ __forceinline__ float fast_exp2(float x) { return __builtin_amdgcn_exp2f(x); }
__device__ __forceinline__ float fast_rcp(float x)  { return __builtin_amdgcn_rcpf(x); }

// ---------------------------------------------------------------------------
// Projection v3 (unchanged): split-K=4 into 4 SEPARATE buffers.
// grid = (NROWS/32, KSPLIT, 2) = 512 blocks (2/CU, 8 waves/CU).
// RANK-SLOT PERMUTATION: slots {4tx+j} hold logical ranks {tx+16j};
// pair_kernel permutes the weight vectors to match (sum over r invariant).
// ---------------------------------------------------------------------------
__global__ __launch_bounds__(256)
void proj_kernel(const float* __restrict__ tv, const float* __restrict__ sv,
                 const float* __restrict__ Wt, const float* __restrict__ Ws,
                 float* __restrict__ pt, float* __restrict__ ps)
{
    const int which = blockIdx.z;
    const float* X = which ? sv : tv;
    const float* W = which ? Ws : Wt;
    float* P = (which ? ps : pt) + (size_t)blockIdx.y * NROWS * RANK;

    const int row0 = blockIdx.x * 32;
    const int kc   = blockIdx.y * KCH;
    const int tid  = threadIdx.x;
    const int tx   = tid & 15;
    const int ty   = tid >> 4;

    __shared__ float xs[32][132];   // 16.9 KB
    __shared__ float wsm[64][132];  // 33.8 KB

#pragma unroll
    for (int p = 0; p < 4; p++) {
        const int li = p * 256 + tid;
        const int r  = li >> 5;
        const int c  = (li & 31) << 2;
        *(v4f*)&xs[r][c] = *(const v4f*)&X[(size_t)(row0 + r) * DIM + kc + c];
    }
#pragma unroll
    for (int p = 0; p < 8; p++) {
        const int li = p * 256 + tid;
        const int r  = li >> 5;
        const int c  = (li & 31) << 2;
        *(v4f*)&wsm[r][c] = *(const v4f*)&W[(size_t)r * DIM + kc + c];
    }
    __syncthreads();

    float acc[2][4];
#pragma unroll
    for (int i = 0; i < 2; i++)
#pragma unroll
        for (int j = 0; j < 4; j++) acc[i][j] = 0.f;

#pragma unroll 4
    for (int k4 = 0; k4 < KCH; k4 += 4) {
        v4f a[2], b[4];
#pragma unroll
        for (int i = 0; i < 2; i++)
            a[i] = *(const v4f*)&xs[ty + 16 * i][k4];   // broadcast per 16-group
#pragma unroll
        for (int j = 0; j < 4; j++)
            b[j] = *(const v4f*)&wsm[tx + 16 * j][k4];  // 2-way bank: free
#pragma unroll
        for (int i = 0; i < 2; i++)
#pragma unroll
            for (int j = 0; j < 4; j++) {
                acc[i][j] = fmaf(a[i].x, b[j].x, acc[i][j]);
                acc[i][j] = fmaf(a[i].y, b[j].y, acc[i][j]);
                acc[i][j] = fmaf(a[i].z, b[j].z, acc[i][j]);
                acc[i][j] = fmaf(a[i].w, b[j].w, acc[i][j]);
            }
    }

    // slot-permuted vector store: slots 4tx..4tx+3 hold logical ranks tx+16j
#pragma unroll
    for (int i = 0; i < 2; i++) {
        v4f o = {acc[i][0], acc[i][1], acc[i][2], acc[i][3]};
        *(v4f*)&P[(size_t)(row0 + ty + 16 * i) * RANK + tx * 4] = o;
    }
}

// ---------------------------------------------------------------------------
// Pairwise v8: back to the best-measured config (32x64, 256 thr, 1024 blocks)
// with two trans/latency cuts:
//  - 8-way shared reciprocal: quads (i=0,j) and (i=1,j) share one rcp.
//    R = rcp(P0*P1); 1/p_i recovered by partial products (exact algebra).
//    1 rcp per 8 elements (was 2): -16 trans cyc, +6 VALU cyc per 8 elems.
//  - explicit 2-stage register pipeline on LDS reads: fragments for r4+4
//    are ds_read BEFORE computing r4's trans-heavy body, fully unrolled,
//    hiding lgkm latency under exp2 work at fixed occupancy.
// Per 8 elems: 33 VALU + 9 trans (was 30 + 10).
// ---------------------------------------------------------------------------
#define LOADQ(aA_, aB_, bA_, bB_, wA_, wB_, R4)                              \
  {                                                                          \
    const v4f w2_ = *(const v4f*)&wsh2[R4];                                  \
    wA_ = (v2f){w2_.x, w2_.y};                                               \
    wB_ = (v2f){w2_.z, w2_.w};                                               \
    _Pragma("unroll") for (int i_ = 0; i_ < 2; i_++) {                       \
      const v4f av_ = *(const v4f*)&pts[ty + 16 * i_][R4];                   \
      aA_[i_] = (v2f){av_.x, av_.y};                                         \
      aB_[i_] = (v2f){av_.z, av_.w};                                         \
    }                                                                        \
    _Pragma("unroll") for (int j_ = 0; j_ < 4; j_++) {                       \
      const v4f bb_ = *(const v4f*)&sts[tx + 16 * j_][R4];                   \
      bA_[j_] = (v2f){bb_.x, bb_.y};                                         \
      bB_[j_] = (v2f){bb_.z, bb_.w};                                         \
    }                                                                        \
  }

#define COMPQ(aA_, aB_, bA_, bB_, wA_, wB_)                                  \
  _Pragma("unroll") for (int j_ = 0; j_ < 4; j_++) {                         \
    const v2f tA0 = aA_[0] * bA_[j_], tB0 = aB_[0] * bB_[j_];                \
    const v2f tA1 = aA_[1] * bA_[j_], tB1 = aB_[1] * bB_[j_];                \
    const float e00 = fast_exp2(tA0.x), e01 = fast_exp2(tA0.y);              \
    const float e02 = fast_exp2(tB0.x), e03 = fast_exp2(tB0.y);              \
    const float e10 = fast_exp2(tA1.x), e11 = fast_exp2(tA1.y);              \
    const float e12 = fast_exp2(tB1.x), e13 = fast_exp2(tB1.y);              \
    v2f dA0 = {e00, e01}; dA0 += 1.0f;                                       \
    v2f dB0 = {e02, e03}; dB0 += 1.0f;                                       \
    v2f dA1 = {e10, e11}; dA1 += 1.0f;                                       \
    v2f dB1 = {e12, e13}; dB1 += 1.0f;                                       \
    const float p0 = dA0.x * dA0.y, q0 = dB0.x * dB0.y;                      \
    const float p1 = dA1.x * dA1.y, q1 = dB1.x * dB1.y;                      \
    const float P0 = p0 * q0, P1 = p1 * q1;                                  \
    const float R  = fast_rcp(P0 * P1);      /* one rcp / 8 elems */         \
    const float i0 = R * P1, i1 = R * P0;    /* 1/P0, 1/P1 */                \
    const v2f nA0 = tA0 * wA_, nB0 = tB0 * wB_;  /* = z*iw (n-from-t) */     \
    const v2f nA1 = tA1 * wA_, nB1 = tB1 * wB_;                              \
    const float uA0 = fmaf(nA0.y, dA0.x, nA0.x * dA0.y);                     \
    const float uB0 = fmaf(nB0.y, dB0.x, nB0.x * dB0.y);                     \
    const float uA1 = fmaf(nA1.y, dA1.x, nA1.x * dA1.y);                     \
    const float uB1 = fmaf(nB1.y, dB1.x, nB1.x * dB1.y);                     \
    const v2f rr0 = (v2f){q0, p0} * i0;      /* {1/p0, 1/q0} */              \
    const v2f rr1 = (v2f){q1, p1} * i1;      /* {1/p1, 1/q1} */              \
    acc2[0][j_] += rr0 * (v2f){uA0, uB0};                                    \
    acc2[1][j_] += rr1 * (v2f){uA1, uB1};                                    \
  }

__global__ __launch_bounds__(256)
void pair_kernel(const float* __restrict__ pt, const float* __restrict__ ps,
                 const float* __restrict__ wt_out, const float* __restrict__ ws_out,
                 const float* __restrict__ iw, const float* __restrict__ bias_p,
                 float* __restrict__ out)
{
    const int b  = blockIdx.z;
    const int t0 = blockIdx.y * 32;
    const int s0 = blockIdx.x * 64;
    const int tid = threadIdx.x;
    const int tx  = tid & 15;
    const int ty  = tid >> 4;          // 0..15

    __shared__ float pts[32][68];             // pre-scaled by NL2E
    __shared__ float sts[64][68];
    __shared__ __align__(16) float wsh2[64];  // iw (slot-permuted) / NL2E
    __shared__ float wtsh[64];                // wt_out (slot-permuted) / NL2E
    __shared__ float wssh[64];                // ws_out (slot-permuted), raw
    __shared__ float tlsh[32];
    __shared__ float slsh[64];

    const float NL2E = -1.44269504088896340736f;  // -log2(e)
    const float INV_NL2E = -0.6931471805599453f;  // 1/NL2E = -ln(2)

    const size_t SPL = (size_t)NROWS * RANK;
    const float* ptb = pt + ((size_t)b * TDIM + t0) * RANK;
    const float* psb = ps + ((size_t)b * TDIM + s0) * RANK;

    // ---- stage pt rows (sum 4 K-splits, pre-scale by NL2E): 2 v4f/thread ----
#pragma unroll
    for (int p = 0; p < 2; p++) {
        const int li = p * 256 + tid;
        const int r  = li >> 4;
        const int c  = (li & 15) << 2;
        const float* src = ptb + (size_t)r * RANK + c;
        v4f v = *(const v4f*)src;
        v += *(const v4f*)(src + SPL);
        v += *(const v4f*)(src + 2 * SPL);
        v += *(const v4f*)(src + 3 * SPL);
        *(v4f*)&pts[r][c] = v * NL2E;
    }
    // ---- stage ps rows (raw): 4 v4f/thread ----
#pragma unroll
    for (int p = 0; p < 4; p++) {
        const int li = p * 256 + tid;
        const int r  = li >> 4;
        const int c  = (li & 15) << 2;
        const float* src = psb + (size_t)r * RANK + c;
        v4f v = *(const v4f*)src;
        v += *(const v4f*)(src + SPL);
        v += *(const v4f*)(src + 2 * SPL);
        v += *(const v4f*)(src + 3 * SPL);
        *(v4f*)&sts[r][c] = v;
    }
    if (tid < 64) {
        const int lg = (tid >> 2) + 16 * (tid & 3);  // logical rank of slot tid
        wsh2[tid] = iw[lg] * INV_NL2E;     // tA*wsh2 = z*iw  (exact)
        wtsh[tid] = wt_out[lg] * INV_NL2E; // tl = sum pts'*wtsh = sum av*wt
        wssh[tid] = ws_out[lg];
    }
    __syncthreads();

    // per-block linear terms (disjoint waves do the two jobs)
    const float bias = bias_p[0];
    if (tid < 32) {
        float v = 0.f;
#pragma unroll 8
        for (int r = 0; r < RANK; r++) v = fmaf(pts[tid][r], wtsh[r], v);
        tlsh[tid] = v;
    } else if (tid >= 64 && tid < 128) {
        const int s = tid - 64;
        float v = bias;
#pragma unroll 8
        for (int r = 0; r < RANK; r++) v = fmaf(sts[s][r], wssh[r], v);
        slsh[s] = v;   // bias folded in
    }
    __syncthreads();

    v2f acc2[2][4];
#pragma unroll
    for (int i = 0; i < 2; i++)
#pragma unroll
        for (int j = 0; j < 4; j++) acc2[i][j] = (v2f){0.f, 0.f};

    // ---- software-pipelined main loop: load r4+4 before computing r4 ----
    v2f aAx[2], aBx[2], bAx[4], bBx[4], wAx, wBx;
    v2f aAy[2], aBy[2], bAy[4], bBy[4], wAy, wBy;

    LOADQ(aAx, aBx, bAx, bBx, wAx, wBx, 0);
#pragma unroll
    for (int r8 = 0; r8 < RANK; r8 += 8) {
        LOADQ(aAy, aBy, bAy, bBy, wAy, wBy, r8 + 4);
        COMPQ(aAx, aBx, bAx, bBx, wAx, wBx);
        if (r8 + 8 < RANK) {
            LOADQ(aAx, aBx, bAx, bBx, wAx, wBx, r8 + 8);
        }
        COMPQ(aAy, aBy, bAy, bBy, wAy, wBy);
    }

    // epilogue (horizontal add + linear terms; bias already in slsh)
#pragma unroll
    for (int i = 0; i < 2; i++) {
        const int t = t0 + ty + 16 * i;
        const float tl = tlsh[ty + 16 * i];
        float* orow = out + ((size_t)b * TDIM + t) * TDIM + s0;
#pragma unroll
        for (int j = 0; j < 4; j++) {
            orow[tx + 16 * j] = (acc2[i][j].x + acc2[i][j].y) + tl + slsh[tx + 16 * j];
        }
    }
}

// ---------------------------------------------------------------------------
extern "C" void kernel_launch(void* const* d_in, const int* in_sizes, int n_in,
                              void* d_out, int out_size, void* d_ws, size_t ws_size,
                              hipStream_t stream)
{
    const float* tv     = (const float*)d_in[0];  // [2,1024,512]
    const float* sv     = (const float*)d_in[1];  // [2,1024,512]
    const float* Wt     = (const float*)d_in[2];  // [64,512]
    const float* Ws     = (const float*)d_in[3];  // [64,512]
    const float* wt_out = (const float*)d_in[4];  // [64]
    const float* ws_out = (const float*)d_in[5];  // [64]
    const float* iw     = (const float*)d_in[6];  // [64]
    const float* bias   = (const float*)d_in[7];  // scalar
    float* out = (float*)d_out;                   // [2,1024,1024]

    const size_t SPL = (size_t)NROWS * RANK;      // 131072 floats
    float* pt = (float*)d_ws;                     // [KSPLIT][2048][64]
    float* ps = pt + (size_t)KSPLIT * SPL;        // [KSPLIT][2048][64]

    // no memset: every split slot is written exactly once
    dim3 pgrid(NROWS / 32, KSPLIT, 2);            // 512 blocks
    proj_kernel<<<pgrid, 256, 0, stream>>>(tv, sv, Wt, Ws, pt, ps);

    dim3 ggrid(TDIM / 64, TDIM / 32, BB);         // 1024 blocks
    pair_kernel<<<ggrid, 256, 0, stream>>>(pt, ps, wt_out, ws_out, iw, bias, out);
}

// Round 8
// 112.535 us; speedup vs baseline: 1.1623x; 1.1623x over previous
//
#include <hip/hip_runtime.h>

#define DIM    512
#define RANK   64
#define TDIM   1024
#define BB     2
#define NROWS  (BB * TDIM)     // 2048 flattened rows per tensor
#define KSPLIT 4
#define KCH    (DIM / KSPLIT)  // 128 K-columns per proj block

typedef float v4f __attribute__((ext_vector_type(4)));
typedef float v2f __attribute__((ext_vector_type(2)));

__device__ __forceinline__ float fast_exp2(float x) { return __builtin_amdgcn_exp2f(x); }
__device__ __forceinline__ float fast_rcp(float x)  { return __builtin_amdgcn_rcpf(x); }

// ---------------------------------------------------------------------------
// Projection v3: split-K=4 into 4 SEPARATE buffers (no atomics, no memset).
// grid = (NROWS/32, KSPLIT, 2) = 512 blocks (2/CU, 8 waves/CU).
// Tile 32 rows x 64 ranks, K=128 per block, single LDS fill (50.7 KB:
// stride 132 words = 528 B -> 16B-aligned rows, bank offset 4 -> 2-way free).
// RANK-SLOT PERMUTATION: thread (tx,ty) computes logical ranks {tx+16j},
// stores them at slots {4tx+j} so the output store is one v4f per row.
// pair_kernel consumes the same permutation (sum over r is perm-invariant)
// by permuting iw/wt_out/ws_out at load: logical(c) = (c>>2) + 16*(c&3).
// ---------------------------------------------------------------------------
__global__ __launch_bounds__(256)
void proj_kernel(const float* __restrict__ tv, const float* __restrict__ sv,
                 const float* __restrict__ Wt, const float* __restrict__ Ws,
                 float* __restrict__ pt, float* __restrict__ ps)
{
    const int which = blockIdx.z;
    const float* X = which ? sv : tv;
    const float* W = which ? Ws : Wt;
    float* P = (which ? ps : pt) + (size_t)blockIdx.y * NROWS * RANK;

    const int row0 = blockIdx.x * 32;
    const int kc   = blockIdx.y * KCH;
    const int tid  = threadIdx.x;
    const int tx   = tid & 15;
    const int ty   = tid >> 4;

    __shared__ float xs[32][132];   // 16.9 KB
    __shared__ float wsm[64][132];  // 33.8 KB

    // ---- stage X tile: 32 rows x 128 cols = 1024 v4f, 4 per thread ----
#pragma unroll
    for (int p = 0; p < 4; p++) {
        const int li = p * 256 + tid;     // 0..1023
        const int r  = li >> 5;           // 0..31
        const int c  = (li & 31) << 2;    // 0..124
        *(v4f*)&xs[r][c] = *(const v4f*)&X[(size_t)(row0 + r) * DIM + kc + c];
    }
    // ---- stage W tile: 64 ranks x 128 cols = 2048 v4f, 8 per thread ----
#pragma unroll
    for (int p = 0; p < 8; p++) {
        const int li = p * 256 + tid;     // 0..2047
        const int r  = li >> 5;           // 0..63
        const int c  = (li & 31) << 2;
        *(v4f*)&wsm[r][c] = *(const v4f*)&W[(size_t)r * DIM + kc + c];
    }
    __syncthreads();

    float acc[2][4];
#pragma unroll
    for (int i = 0; i < 2; i++)
#pragma unroll
        for (int j = 0; j < 4; j++) acc[i][j] = 0.f;

#pragma unroll 4
    for (int k4 = 0; k4 < KCH; k4 += 4) {
        v4f a[2], b[4];
#pragma unroll
        for (int i = 0; i < 2; i++)
            a[i] = *(const v4f*)&xs[ty + 16 * i][k4];   // broadcast per 16-group
#pragma unroll
        for (int j = 0; j < 4; j++)
            b[j] = *(const v4f*)&wsm[tx + 16 * j][k4];  // 2-way bank: free
#pragma unroll
        for (int i = 0; i < 2; i++)
#pragma unroll
            for (int j = 0; j < 4; j++) {
                acc[i][j] = fmaf(a[i].x, b[j].x, acc[i][j]);
                acc[i][j] = fmaf(a[i].y, b[j].y, acc[i][j]);
                acc[i][j] = fmaf(a[i].z, b[j].z, acc[i][j]);
                acc[i][j] = fmaf(a[i].w, b[j].w, acc[i][j]);
            }
    }

    // slot-permuted vector store: slots 4tx..4tx+3 hold logical ranks tx+16j
#pragma unroll
    for (int i = 0; i < 2; i++) {
        v4f o = {acc[i][0], acc[i][1], acc[i][2], acc[i][3]};
        *(v4f*)&P[(size_t)(row0 + ty + 16 * i) * RANK + tx * 4] = o;
    }
}

// ---------------------------------------------------------------------------
// Pairwise (round-2 best, reverted verbatim):
// out[b][t][s] = sum_r iw[r]*silu(pt[b,t,r]*ps[b,s,r]) + tl[b,t] + sl[b,s] + bias
// grid = (16, 32, 2) = 1024 blocks. Tile 32(t) x 64(s), micro 2x4.
// Prologue sums the 4 K-split buffers; weight vectors loaded PERMUTED to
// match proj's rank-slot layout.
// Inner loop: packed-f32 (v_pk_*_f32) + 4-way shared reciprocal:
//   r = rcp(d0*d1*d2*d3); sig_k recovered via partial products (exact).
// Measured: 43.9 us, VGPR 40, VALUBusy 62.5% — trans-pipe-busy floor at
// every occupancy tried (2-4 waves/SIMD); VGPR-heavy pipelining regresses.
// ---------------------------------------------------------------------------
__global__ __launch_bounds__(256)
void pair_kernel(const float* __restrict__ pt, const float* __restrict__ ps,
                 const float* __restrict__ wt_out, const float* __restrict__ ws_out,
                 const float* __restrict__ iw, const float* __restrict__ bias_p,
                 float* __restrict__ out)
{
    const int b  = blockIdx.z;
    const int t0 = blockIdx.y * 32;
    const int s0 = blockIdx.x * 64;
    const int tid = threadIdx.x;
    const int tx  = tid & 15;
    const int ty  = tid >> 4;

    __shared__ float pts[32][68];
    __shared__ float sts[64][68];
    __shared__ __align__(16) float wsh[64];   // iw, slot-permuted
    __shared__ float wtsh[64];                // wt_out, slot-permuted
    __shared__ float wssh[64];                // ws_out, slot-permuted
    __shared__ float tlsh[32];
    __shared__ float slsh[64];

    const size_t SPL = (size_t)NROWS * RANK;
    const float* ptb = pt + ((size_t)b * TDIM + t0) * RANK;
    const float* psb = ps + ((size_t)b * TDIM + s0) * RANK;

    // ---- stage pt rows (sum 4 K-splits): 32 rows x 16 v4f -> 2/thread ----
#pragma unroll
    for (int p = 0; p < 2; p++) {
        const int li = p * 256 + tid;
        const int r  = li >> 4;
        const int c  = (li & 15) << 2;
        const float* src = ptb + (size_t)r * RANK + c;
        v4f v = *(const v4f*)src;
        v += *(const v4f*)(src + SPL);
        v += *(const v4f*)(src + 2 * SPL);
        v += *(const v4f*)(src + 3 * SPL);
        *(v4f*)&pts[r][c] = v;
    }
    // ---- stage ps rows: 64 rows x 16 v4f -> 4/thread ----
#pragma unroll
    for (int p = 0; p < 4; p++) {
        const int li = p * 256 + tid;
        const int r  = li >> 4;
        const int c  = (li & 15) << 2;
        const float* src = psb + (size_t)r * RANK + c;
        v4f v = *(const v4f*)src;
        v += *(const v4f*)(src + SPL);
        v += *(const v4f*)(src + 2 * SPL);
        v += *(const v4f*)(src + 3 * SPL);
        *(v4f*)&sts[r][c] = v;
    }
    if (tid < 64) {
        const int lg = (tid >> 2) + 16 * (tid & 3);  // logical rank of slot tid
        wsh[tid]  = iw[lg];
        wtsh[tid] = wt_out[lg];
        wssh[tid] = ws_out[lg];
    }
    __syncthreads();

    // per-block linear terms (slot-space dot with permuted weights)
    if (tid < 32) {
        float v = 0.f;
#pragma unroll 8
        for (int r = 0; r < RANK; r++) v = fmaf(pts[tid][r], wtsh[r], v);
        tlsh[tid] = v;
    } else if (tid >= 64 && tid < 128) {
        const int s = tid - 64;
        float v = 0.f;
#pragma unroll 8
        for (int r = 0; r < RANK; r++) v = fmaf(sts[s][r], wssh[r], v);
        slsh[s] = v;
    }
    __syncthreads();

    const float bias = bias_p[0];
    const float NL2E = -1.44269504088896340736f;  // -log2(e)

    float acc[2][4];
#pragma unroll
    for (int i = 0; i < 2; i++)
#pragma unroll
        for (int j = 0; j < 4; j++) acc[i][j] = 0.f;

    for (int r4 = 0; r4 < RANK; r4 += 4) {
        const v4f wv4 = *(const v4f*)&wsh[r4];
        const v2f wvA = {wv4.x, wv4.y};
        const v2f wvB = {wv4.z, wv4.w};

        v2f a2[2][2], wa[2][2];
#pragma unroll
        for (int i = 0; i < 2; i++) {
            const v4f av = *(const v4f*)&pts[ty + 16 * i][r4];  // broadcast
            const v2f aA = {av.x, av.y};
            const v2f aB = {av.z, av.w};
            a2[i][0] = aA * NL2E;   // feeds exp2
            a2[i][1] = aB * NL2E;
            wa[i][0] = aA * wvA;    // feeds w*z
            wa[i][1] = aB * wvB;
        }
        v2f bv[4][2];
#pragma unroll
        for (int j = 0; j < 4; j++) {
            const v4f bb = *(const v4f*)&sts[tx + 16 * j][r4];  // 2-way bank: free
            bv[j][0] = (v2f){bb.x, bb.y};
            bv[j][1] = (v2f){bb.z, bb.w};
        }

#pragma unroll
        for (int i = 0; i < 2; i++)
#pragma unroll
            for (int j = 0; j < 4; j++) {
                const v2f tA = a2[i][0] * bv[j][0];     // pk_mul
                const v2f tB = a2[i][1] * bv[j][1];
                const float e0 = fast_exp2(tA.x);
                const float e1 = fast_exp2(tA.y);
                const float e2 = fast_exp2(tB.x);
                const float e3 = fast_exp2(tB.y);
                v2f dA = {e0, e1};  dA += 1.0f;          // pk_add
                v2f dB = {e2, e3};  dB += 1.0f;
                const float pA = dA.x * dA.y;
                const float pB = dB.x * dB.y;
                const float r  = fast_rcp(pA * pB);      // one rcp / 4 elems
                const v2f nA = wa[i][0] * bv[j][0];      // pk_mul
                const v2f nB = wa[i][1] * bv[j][1];
                const float uA = fmaf(nA.y, dA.x, nA.x * dA.y);
                const float uB = fmaf(nB.y, dB.x, nB.x * dB.y);
                const float rA = r * pB;                 // = 1/(d0*d1)
                const float rB = r * pA;                 // = 1/(d2*d3)
                acc[i][j] = fmaf(rA, uA, acc[i][j]);
                acc[i][j] = fmaf(rB, uB, acc[i][j]);
            }
    }

    // epilogue
#pragma unroll
    for (int i = 0; i < 2; i++) {
        const int t = t0 + ty + 16 * i;
        const float tl = tlsh[ty + 16 * i];
        float* orow = out + ((size_t)b * TDIM + t) * TDIM + s0;
#pragma unroll
        for (int j = 0; j < 4; j++) {
            orow[tx + 16 * j] = acc[i][j] + tl + slsh[tx + 16 * j] + bias;
        }
    }
}

// ---------------------------------------------------------------------------
extern "C" void kernel_launch(void* const* d_in, const int* in_sizes, int n_in,
                              void* d_out, int out_size, void* d_ws, size_t ws_size,
                              hipStream_t stream)
{
    const float* tv     = (const float*)d_in[0];  // [2,1024,512]
    const float* sv     = (const float*)d_in[1];  // [2,1024,512]
    const float* Wt     = (const float*)d_in[2];  // [64,512]
    const float* Ws     = (const float*)d_in[3];  // [64,512]
    const float* wt_out = (const float*)d_in[4];  // [64]
    const float* ws_out = (const float*)d_in[5];  // [64]
    const float* iw     = (const float*)d_in[6];  // [64]
    const float* bias   = (const float*)d_in[7];  // scalar
    float* out = (float*)d_out;                   // [2,1024,1024]

    const size_t SPL = (size_t)NROWS * RANK;      // 131072 floats
    float* pt = (float*)d_ws;                     // [KSPLIT][2048][64]
    float* ps = pt + (size_t)KSPLIT * SPL;        // [KSPLIT][2048][64]

    // no memset: every split slot is written exactly once
    dim3 pgrid(NROWS / 32, KSPLIT, 2);            // 512 blocks
    proj_kernel<<<pgrid, 256, 0, stream>>>(tv, sv, Wt, Ws, pt, ps);

    dim3 ggrid(TDIM / 64, TDIM / 32, BB);         // 1024 blocks
    pair_kernel<<<ggrid, 256, 0, stream>>>(pt, ps, wt_out, ws_out, iw, bias, out);
}